// Round 1
// 60357.001 us; speedup vs baseline: 1.0115x; 1.0115x over previous
//
#include <hip/hip_runtime.h>

#define B_ 16
#define ENC_D_ 512
#define ENC_T_ 256
#define FEAT_D_ 513
#define DEC_T_ 512
#define ATT_ 128
#define NWG_ 256

typedef unsigned short u16;
typedef __attribute__((ext_vector_type(8))) short bf16x8;
typedef __attribute__((ext_vector_type(4))) float f32x4;

// ---- LDS arena offsets (bytes) ----
#define S_WIH1 0            // [16][776] u16
#define S_WHH1 24832        // [16][1032] u16
#define S_WIH2 57856        // [16][1032] u16 (cols 0..1024 only; ctx cols live in VGPRs)
#define S_WHH2 90880        // [16][1032] u16
#define S_RED  123904       // float[2048]
#define S_ATT  132096       // float[2][128]
#define S_VS   133120       // float[128]
#define S_E    133632       // float[256] energies
#define S_ALN  134656       // float[256] persistent align (attn WGs)
#define S_CUM  135680       // float[256] persistent cum   (attn WGs)
#define S_SRED 136704       // float[8]
#define S_CONVF 136736      // u16 [256][32]  convf[t'][c]  (16-B aligned rows)
#define S_WCV  153120       // u16 [32][62]   conv weights
#define LDS_BYTES 157088

__device__ __forceinline__ float b2f(u16 x) {
  unsigned u = ((unsigned)x) << 16;
  return __builtin_bit_cast(float, u);
}
__device__ __forceinline__ u16 f2b(float f) {
  unsigned u = __builtin_bit_cast(unsigned, f);
  u += 0x7FFFu + ((u >> 16) & 1u);
  return (u16)(u >> 16);
}
__device__ __forceinline__ float ldin(const void* p, long i, bool f32) {
  return f32 ? ((const float*)p)[i] : b2f(((const u16*)p)[i]);
}
__device__ __forceinline__ float sigm(float x) {
  return __builtin_amdgcn_rcpf(1.f + __expf(-x));
}
__device__ __forceinline__ float tanh_fast(float x) {
  float e = __expf(2.f * x);
  return 1.f - 2.f * __builtin_amdgcn_rcpf(e + 1.f);
}

// two-level grid barrier: 8 sub-counters (one per XCD-ish group of 32 WGs) + root.
// monotonic counters -> no reset race. bar layout (u32 words):
//   sub[g] at bar[g*32] (g=0..7), root at bar[256], gen at bar[288]
__device__ __forceinline__ void gbar(unsigned* bar, int grp, unsigned& mygen) {
  __threadfence();
  __syncthreads();
  ++mygen;
  if (threadIdx.x == 0) {
    unsigned* sub = bar + (grp << 5);
    unsigned* root = bar + 256;
    unsigned* gen = bar + 288;
    unsigned old = __hip_atomic_fetch_add(sub, 1u, __ATOMIC_ACQ_REL, __HIP_MEMORY_SCOPE_AGENT);
    if (old + 1u == (mygen << 5)) {
      unsigned rold = __hip_atomic_fetch_add(root, 1u, __ATOMIC_ACQ_REL, __HIP_MEMORY_SCOPE_AGENT);
      if (rold + 1u == (mygen << 3))
        __hip_atomic_store(gen, mygen, __ATOMIC_RELEASE, __HIP_MEMORY_SCOPE_AGENT);
    }
    while (__hip_atomic_load(gen, __ATOMIC_RELAXED, __HIP_MEMORY_SCOPE_AGENT) < mygen)
      __builtin_amdgcn_s_sleep(2);
  }
  __syncthreads();
  __threadfence();
}

// float dtype detect: 0 = bf16 inputs, 1 = fp32 inputs
__global__ void k_detect(const u16* __restrict__ w, int* flag) {
  __shared__ int cnt;
  if (threadIdx.x == 0) cnt = 0;
  __syncthreads();
  int c = 0;
  for (int i = threadIdx.x; i < 512; i += 256) {
    u16 v = w[2 * i];
    int e = (v >> 7) & 0xFF;
    if (e >= 80 && e <= 140) c++;
  }
  atomicAdd(&cnt, c);
  __syncthreads();
  if (threadIdx.x == 0) *flag = (cnt >= 384) ? 0 : 1;
}

// encoding_lengths format detect
__global__ void k_lens(const void* __restrict__ raw, int* __restrict__ lens_out) {
  if (threadIdx.x != 0 || blockIdx.x != 0) return;
  const int* i32 = (const int*)raw;
  const long long* i64 = (const long long*)raw;
  const float* f32 = (const float*)raw;
  const double* f64 = (const double*)raw;
  bool ok;
  ok = true;
  for (int b = 0; b < B_; ++b) { int v = i32[b]; if (v < 1 || v > ENC_T_) ok = false; }
  if (ok) { for (int b = 0; b < B_; ++b) lens_out[b] = i32[b]; return; }
  ok = true;
  for (int b = 0; b < B_; ++b) { long long v = i64[b]; if (v < 1 || v > ENC_T_) ok = false; }
  if (ok) { for (int b = 0; b < B_; ++b) lens_out[b] = (int)i64[b]; return; }
  ok = true;
  for (int b = 0; b < B_; ++b) { float x = f32[b]; if (!(x >= 1.f && x <= 256.f && x == floorf(x))) ok = false; }
  if (ok) { for (int b = 0; b < B_; ++b) lens_out[b] = (int)f32[b]; return; }
  ok = true;
  for (int b = 0; b < B_; ++b) { double x = f64[b]; if (!(x >= 1.0 && x <= 256.0 && x == floor(x))) ok = false; }
  if (ok) { for (int b = 0; b < B_; ++b) lens_out[b] = (int)f64[b]; return; }
  for (int b = 0; b < B_; ++b) {
    int v = i32[b];
    lens_out[b] = v < 1 ? 1 : (v > ENC_T_ ? ENC_T_ : v);
  }
}

// convert one tensor to bf16 in ws
__global__ void k_cvt(const void* __restrict__ src, u16* __restrict__ dst, int n,
                      const int* __restrict__ flag) {
  bool f32 = (*flag) != 0;
  int stride = blockDim.x * gridDim.x;
  for (int i = threadIdx.x + blockIdx.x * blockDim.x; i < n; i += stride)
    dst[i] = f32 ? f2b(((const float*)src)[i]) : ((const u16*)src)[i];
}

// init: zero states + barrier words
__global__ void k_init(u16* h1g, u16* h2g, u16* ctxg, float* c1g, float* c2g, unsigned* bar) {
  int tid = threadIdx.x + blockIdx.x * blockDim.x;
  int stride = blockDim.x * gridDim.x;
  for (int i = tid; i < 2 * B_ * 1024; i += stride) h1g[i] = 0;
  for (int i = tid; i < B_ * 1024; i += stride) h2g[i] = 0;
  for (int i = tid; i < 2 * B_ * 512; i += stride) ctxg[i] = 0;
  for (int i = tid; i < B_ * 1024; i += stride) { c1g[i] = 0.f; c2g[i] = 0.f; }
  for (int i = tid; i < 512; i += stride) bar[i] = 0u;
}

// prenet for all timesteps (teacher-forced, recurrence-free), bf16 out
__global__ __launch_bounds__(256) void k_prenet(const void* __restrict__ feats,
                                                const void* __restrict__ go,
                                                const void* __restrict__ w0,
                                                const void* __restrict__ w1,
                                                u16* __restrict__ pre,
                                                const int* __restrict__ flag) {
  const bool f32 = (*flag) != 0;
  int t = blockIdx.x, tid = threadIdx.x;
  __shared__ __align__(16) float din[FEAT_D_][16];
  __shared__ __align__(16) float o1[256][16];
  for (int idx = tid; idx < 16 * FEAT_D_; idx += 256) {
    int f = idx >> 4, b = idx & 15;
    float v = (t == 0) ? ldin(go, f, f32)
                       : ldin(feats, ((long)b * FEAT_D_ + f) * DEC_T_ + (t - 1), f32);
    din[f][b] = v;
  }
  __syncthreads();
  float acc[16];
#pragma unroll
  for (int b = 0; b < 16; ++b) acc[b] = 0.f;
  for (int f = 0; f < FEAT_D_; ++f) {
    float w = ldin(w0, (long)tid * FEAT_D_ + f, f32);
#pragma unroll
    for (int b = 0; b < 16; ++b) acc[b] += w * din[f][b];
  }
#pragma unroll
  for (int b = 0; b < 16; ++b) o1[tid][b] = fmaxf(acc[b], 0.f);
  __syncthreads();
#pragma unroll
  for (int b = 0; b < 16; ++b) acc[b] = 0.f;
  for (int r1 = 0; r1 < 256; ++r1) {
    float w = ldin(w1, (long)tid * 256 + r1, f32);
#pragma unroll
    for (int b = 0; b < 16; ++b) acc[b] += w * o1[r1][b];
  }
#pragma unroll
  for (int b = 0; b < 16; ++b)
    pre[((long)t * 16 + b) * 256 + tid] = f2b(fmaxf(acc[b], 0.f));
}

// encoder transpose (bf16) + processed-memory. NEW pm layout: [b][a][t'] (t' contiguous)
__global__ __launch_bounds__(256) void k_mem(const void* __restrict__ enc,
                                             const void* __restrict__ wmem,
                                             u16* __restrict__ mem_t,
                                             float* __restrict__ pm,
                                             const int* __restrict__ flag) {
  const bool f32 = (*flag) != 0;
  int b = blockIdx.x >> 4, tc = blockIdx.x & 15;
  int t0 = tc * 16, tid = threadIdx.x;
  __shared__ __align__(16) float et[16][ENC_D_];
  for (int idx = tid; idx < ENC_D_ * 16; idx += 256) {
    int d = idx >> 4, i = idx & 15;
    et[i][d] = ldin(enc, ((long)b * ENC_D_ + d) * ENC_T_ + t0 + i, f32);
  }
  __syncthreads();
  for (int idx = tid; idx < 16 * ENC_D_; idx += 256) {
    int i = idx >> 9, d = idx & 511;
    mem_t[((long)b * ENC_T_ + t0 + i) * ENC_D_ + d] = f2b(et[i][d]);
  }
  int a = tid & 127;
#pragma unroll 1
  for (int jj = 0; jj < 8; ++jj) {
    int i = ((tid >> 7) << 3) + jj;
    float s = 0.f;
    for (int d = 0; d < ENC_D_; ++d)
      s += ldin(wmem, (long)a * ENC_D_ + d, f32) * et[i][d];
    pm[((long)b * ATT_ + a) * ENC_T_ + t0 + i] = s;
  }
}

// ---------------- persistent decoder ----------------
__global__ __launch_bounds__(256) void k_main(
    const u16* __restrict__ wih1, const u16* __restrict__ whh1, const u16* __restrict__ b1,
    const u16* __restrict__ wih2, const u16* __restrict__ whh2, const u16* __restrict__ b2,
    const u16* __restrict__ wq, const u16* __restrict__ wconv, const u16* __restrict__ wdense,
    const u16* __restrict__ vv, const u16* __restrict__ wproj, const u16* __restrict__ bproj,
    const int* __restrict__ lens,
    const u16* __restrict__ pre, const u16* __restrict__ mem_t, const float* __restrict__ pm,
    u16* h1g, u16* h2g, u16* ctxg, float* c1g, float* c2g,
    unsigned* bar, float* outf, float* outa) {
  extern __shared__ __align__(16) char smem[];
  u16* s_wih1 = (u16*)(smem + S_WIH1);
  u16* s_whh1 = (u16*)(smem + S_WHH1);
  u16* s_wih2 = (u16*)(smem + S_WIH2);
  u16* s_whh2 = (u16*)(smem + S_WHH2);
  float* red_f = (float*)(smem + S_RED);
  float (*red)[64][4] = (float(*)[64][4])red_f;
  float (*att_s)[128] = (float(*)[128])(smem + S_ATT);
  float* v_s = (float*)(smem + S_VS);
  float* e_s = (float*)(smem + S_E);
  float* align_s = (float*)(smem + S_ALN);
  float* cum_s = (float*)(smem + S_CUM);
  float* sred = (float*)(smem + S_SRED);
  u16* convf = (u16*)(smem + S_CONVF);
  u16* s_wcv = (u16*)(smem + S_WCV);

  const int wg = blockIdx.x, tid = threadIdx.x;
  const int wid = tid >> 6, lane = tid & 63;
  const int m = lane & 15, q = lane >> 4;
  const int u0 = wg << 2;
  const int bb = m;
  const int grp = wg & 7;

  // ---- stage weight rows into LDS (wih2: only cols 0..1024) ----
  for (int r = 0; r < 4; ++r) {
    int m2 = wid * 4 + r;
    int growr = ((m2 >> 2) << 10) + u0 + (m2 & 3);
    {
      const u16* s = wih1 + (long)growr * 768; u16* d = s_wih1 + m2 * 776;
      for (int c = lane; c < 96; c += 64) *(bf16x8*)(d + c * 8) = *(const bf16x8*)(s + c * 8);
    }
    {
      const u16* s = whh1 + (long)growr * 1024; u16* d = s_whh1 + m2 * 1032;
      for (int c = lane; c < 128; c += 64) *(bf16x8*)(d + c * 8) = *(const bf16x8*)(s + c * 8);
    }
    {
      const u16* s = wih2 + (long)growr * 1536; u16* d = s_wih2 + m2 * 1032;
      for (int c = lane; c < 128; c += 64) *(bf16x8*)(d + c * 8) = *(const bf16x8*)(s + c * 8);
    }
    {
      const u16* s = whh2 + (long)growr * 1024; u16* d = s_whh2 + m2 * 1032;
      for (int c = lane; c < 128; c += 64) *(bf16x8*)(d + c * 8) = *(const bf16x8*)(s + c * 8);
    }
  }
  // Wih2 ctx-columns (1024..1536) per-lane A-fragments in VGPRs
  bf16x8 a2hi[4];
  {
    int growr = ((m >> 2) << 10) + u0 + (m & 3);
#pragma unroll
    for (int kb = 0; kb < 4; ++kb) {
      int k0 = ((wid * 4 + kb) << 5) + (q << 3);
      a2hi[kb] = *(const bf16x8*)(wih2 + (long)growr * 1536 + 1024 + k0);
    }
  }
  // conv weights + v to LDS; attn WGs init persistent align/cum
  for (int i = tid; i < 32 * 62; i += 256) s_wcv[i] = wconv[i];
  if (tid < 128) v_s[tid] = b2f(vv[tid]);
  if (wg < B_) {
    for (int i = tid; i < ENC_T_; i += 256) {
      float v = (i == 0) ? 1.f : 0.f;
      align_s[i] = v; cum_s[i] = v;
    }
  }
  const int len_b = (wg < B_) ? lens[wg] : 0;
  __syncthreads();

  unsigned mygen = 0;
  f32x4 zero4; zero4[0] = zero4[1] = zero4[2] = zero4[3] = 0.f;
  f32x4 acc2 = zero4;

  const u16* a1_ih = s_wih1 + m * 776;
  const u16* a1_hh = s_whh1 + m * 1032;
  const u16* a2_ih = s_wih2 + m * 1032;
  const u16* a2_hh = s_whh2 + m * 1032;

#pragma unroll 1
  for (int t = 0; t < DEC_T_; ++t) {
    const int cb = t & 1, pb = cb ^ 1;
    // ================= PHASE A =================
    // (1) finish gates2(t-1): += Wih2[:,1024:1536] @ ctx_{t-1}; update h2,c2
    if (t > 0) {
      const u16* brow = ctxg + pb * (B_ * 512) + bb * 512;
#pragma unroll
      for (int kb = 0; kb < 4; ++kb) {
        int k0 = ((wid * 4 + kb) << 5) + (q << 3);
        acc2 = __builtin_amdgcn_mfma_f32_16x16x32_bf16(
            a2hi[kb], *(const bf16x8*)(brow + k0), acc2, 0, 0, 0);
      }
      __syncthreads();
      *(f32x4*)&red[wid][lane][0] = acc2;
      __syncthreads();
      if (tid < 64) {
        int u = tid >> 4, bi = tid & 15;
        float gi = 0, gf = 0, gg = 0, go = 0;
#pragma unroll
        for (int w = 0; w < 4; ++w) {
          gi += red[w][bi][u];
          gf += red[w][16 + bi][u];
          gg += red[w][32 + bi][u];
          go += red[w][48 + bi][u];
        }
        int unit = u0 + u;
        gi += b2f(b2[unit]); gf += b2f(b2[1024 + unit]);
        gg += b2f(b2[2048 + unit]); go += b2f(b2[3072 + unit]);
        float cold = c2g[bi * 1024 + unit];
        float cn = sigm(gf) * cold + sigm(gi) * tanh_fast(gg);
        float hn = sigm(go) * tanh_fast(cn);
        c2g[bi * 1024 + unit] = cn;
        h2g[bi * 1024 + unit] = f2b(hn);
      }
      acc2 = zero4;
    }
    // (2) location conv for own batch -> convf[t'][c] (attn WGs only; LDS-local)
    if (wg < B_) {
      int c = tid >> 3;
      int tch = (tid & 7) << 5;
      float w0[31], w1[31];
      const u16* wc = s_wcv + c * 62;
#pragma unroll
      for (int k = 0; k < 31; ++k) { w0[k] = b2f(wc[k]); w1[k] = b2f(wc[31 + k]); }
#pragma unroll 1
      for (int sub = 0; sub < 4; ++sub) {
        int tb = tch + (sub << 3);
        float xa[38], xc[38];
#pragma unroll
        for (int j = 0; j < 38; ++j) {
          int idx = tb + j - 15;
          bool ok = (idx >= 0) && (idx < ENC_T_);
          xa[j] = ok ? align_s[idx] : 0.f;
          xc[j] = ok ? cum_s[idx] : 0.f;
        }
        float acc[8];
#pragma unroll
        for (int j = 0; j < 8; ++j) acc[j] = 0.f;
#pragma unroll
        for (int k = 0; k < 31; ++k) {
#pragma unroll
          for (int j = 0; j < 8; ++j)
            acc[j] = fmaf(w0[k], xa[j + k], fmaf(w1[k], xc[j + k], acc[j]));
        }
#pragma unroll
        for (int j = 0; j < 8; ++j) convf[(tb + j) * 32 + c] = f2b(acc[j]);
      }
    }
    // (3) gates1: Wih1 @ [pre_t | ctx_{t-1}] + Whh1 @ h1_{t-1}; update h1,c1
    {
      f32x4 acc1 = zero4;
      const u16* b_pre = pre + ((long)t * B_ + bb) * 256;
      const u16* b_ctx = ctxg + pb * (B_ * 512) + bb * 512 - 256;
      const u16* b_h1 = h1g + pb * (B_ * 1024) + bb * 1024 - 768;
#pragma unroll 1
      for (int kb = wid * 14; kb < wid * 14 + 14; ++kb) {
        int k0 = (kb << 5) + (q << 3);
        const u16* ap = (k0 < 768) ? (a1_ih + k0) : (a1_hh + (k0 - 768));
        const u16* bp = (k0 < 256) ? (b_pre + k0) : (k0 < 768) ? (b_ctx + k0) : (b_h1 + k0);
        acc1 = __builtin_amdgcn_mfma_f32_16x16x32_bf16(
            *(const bf16x8*)ap, *(const bf16x8*)bp, acc1, 0, 0, 0);
      }
      __syncthreads();
      *(f32x4*)&red[wid][lane][0] = acc1;
      __syncthreads();
      if (tid < 64) {
        int u = tid >> 4, bi = tid & 15;
        float gi = 0, gf = 0, gg = 0, go = 0;
#pragma unroll
        for (int w = 0; w < 4; ++w) {
          gi += red[w][bi][u];
          gf += red[w][16 + bi][u];
          gg += red[w][32 + bi][u];
          go += red[w][48 + bi][u];
        }
        int unit = u0 + u;
        gi += b2f(b1[unit]); gf += b2f(b1[1024 + unit]);
        gg += b2f(b1[2048 + unit]); go += b2f(b1[3072 + unit]);
        float cold = c1g[bi * 1024 + unit];
        float cn = sigm(gf) * cold + sigm(gi) * tanh_fast(gg);
        float hn = sigm(go) * tanh_fast(cn);
        c1g[bi * 1024 + unit] = cn;
        h1g[cb * (B_ * 1024) + bi * 1024 + unit] = f2b(hn);
      }
    }
    gbar(bar, grp, mygen);
    // ================= PHASE B =================
    if (wg < B_) {
      const int ab = wg;
      // query projection
      {
        int a = tid & 127, h = tid >> 7;
        const u16* wr = wq + (long)a * 1024 + h * 512;
        const u16* hr = h1g + cb * (B_ * 1024) + ab * 1024 + h * 512;
        float p = 0.f;
        for (int k = 0; k < 512; k += 8) {
          bf16x8 w8 = *(const bf16x8*)(wr + k);
          bf16x8 h8 = *(const bf16x8*)(hr + k);
#pragma unroll
          for (int j = 0; j < 8; ++j) p += b2f((u16)w8[j]) * b2f((u16)h8[j]);
        }
        att_s[h][a] = p;
      }
      __syncthreads();
      if (tid < 128) att_s[0][tid] += att_s[1][tid];
      __syncthreads();
      // energies: lf via MFMA (wdense[a][c] x convf[t'][c]) + pm + pq -> tanh -> dot v
      {
        const int col = lane & 15, hi2 = lane >> 4;
#pragma unroll 1
        for (int ti = 0; ti < 4; ++ti) {
          int t0 = (wid * 4 + ti) << 4;
          if (t0 >= len_b) break;
          bf16x8 bfrag = *(const bf16x8*)(convf + (t0 + col) * 32 + (hi2 << 3));
          float eacc = 0.f;
#pragma unroll
          for (int at = 0; at < 8; ++at) {
            bf16x8 afrag = *(const bf16x8*)(wdense + ((at * 16 + col) << 5) + (hi2 << 3));
            f32x4 lf = __builtin_amdgcn_mfma_f32_16x16x32_bf16(afrag, bfrag, zero4, 0, 0, 0);
#pragma unroll
            for (int r = 0; r < 4; ++r) {
              int a = at * 16 + (hi2 << 2) + r;
              float s = lf[r] + pm[((long)ab * ATT_ + a) * ENC_T_ + t0 + col] + att_s[0][a];
              eacc = fmaf(v_s[a], tanh_fast(s), eacc);
            }
          }
          eacc += __shfl_xor(eacc, 16);
          eacc += __shfl_xor(eacc, 32);
          if (hi2 == 0) e_s[t0 + col] = eacc;
        }
      }
      __syncthreads();
      // softmax over 256 positions
      float e = (tid < len_b) ? e_s[tid] : -1e9f;
      float mx = e;
#pragma unroll
      for (int off = 32; off; off >>= 1) mx = fmaxf(mx, __shfl_xor(mx, off));
      if (lane == 0) sred[wid] = mx;
      __syncthreads();
      mx = fmaxf(fmaxf(sred[0], sred[1]), fmaxf(sred[2], sred[3]));
      float ex = __expf(e - mx);
      float sm = ex;
#pragma unroll
      for (int off = 32; off; off >>= 1) sm += __shfl_xor(sm, off);
      if (lane == 0) sred[4 + wid] = sm;
      __syncthreads();
      sm = sred[4] + sred[5] + sred[6] + sred[7];
      float al = ex / sm;
      align_s[tid] = al;
      cum_s[tid] += al;
      outa[((long)ab * ENC_T_ + tid) * DEC_T_ + t] = al;
      __syncthreads();
      {
        // ctx = align @ mem_t (len-clamped; align beyond len is exactly 0)
        int g = tid & 63, qd = tid >> 6;
        const u16* mt = mem_t + (long)ab * (ENC_T_ * ENC_D_) + g * 8;
        float a8[8];
#pragma unroll
        for (int j = 0; j < 8; ++j) a8[j] = 0.f;
        int tp0 = qd * 64;
        int tpe = tp0 + 64;
        if (tpe > len_b) tpe = (len_b > tp0) ? len_b : tp0;
#pragma unroll 2
        for (int tp = tp0; tp < tpe; ++tp) {
          float av = align_s[tp];
          bf16x8 m8 = *(const bf16x8*)(mt + (long)tp * ENC_D_);
#pragma unroll
          for (int j = 0; j < 8; ++j) a8[j] = fmaf(av, b2f((u16)m8[j]), a8[j]);
        }
#pragma unroll
        for (int j = 0; j < 8; ++j) red_f[qd * 512 + g * 8 + j] = a8[j];
        __syncthreads();
        for (int d = tid; d < 512; d += 256) {
          float s = red_f[d] + red_f[512 + d] + red_f[1024 + d] + red_f[1536 + d];
          ctxg[cb * (B_ * 512) + ab * 512 + d] = f2b(s);
        }
      }
    }
    if (wg >= 16 && wg < 49 && t > 0) {
      // proj(t-1)
      int tt = wg - 16, r0 = tt << 4;
      int rowp = r0 + m;
      int rowc = rowp > 512 ? 512 : rowp;
      const u16* ar = wproj + (long)rowc * 1536;
      const u16* br_h2 = h2g + bb * 1024;
      const u16* br_ctx = ctxg + pb * (B_ * 512) + bb * 512 - 1024;
      f32x4 accp = zero4;
#pragma unroll 1
      for (int kb = wid * 12; kb < wid * 12 + 12; ++kb) {
        int k0 = (kb << 5) + (q << 3);
        const u16* bp = (k0 < 1024) ? (br_h2 + k0) : (br_ctx + k0);
        accp = __builtin_amdgcn_mfma_f32_16x16x32_bf16(
            *(const bf16x8*)(ar + k0), *(const bf16x8*)bp, accp, 0, 0, 0);
      }
      __syncthreads();
      *(f32x4*)&red[wid][lane][0] = accp;
      __syncthreads();
      {
        int mm = tid >> 4, bi = tid & 15;
        int row = r0 + mm;
        if (row < FEAT_D_) {
          int l = ((mm >> 2) << 4) + bi, r = mm & 3;
          float s = red[0][l][r] + red[1][l][r] + red[2][l][r] + red[3][l][r];
          s += b2f(bproj[row]);
          outf[((long)bi * FEAT_D_ + row) * DEC_T_ + (t - 1)] = s;
        }
      }
    }
    // gates2 partial for step t: Wih2[:,0:1024] @ h1_t + Whh2 @ h2_{t-1}
    {
      const u16* b_h1 = h1g + cb * (B_ * 1024) + bb * 1024;
      const u16* b_h2 = h2g + bb * 1024 - 1024;
#pragma unroll 1
      for (int kb = wid * 16; kb < wid * 16 + 16; ++kb) {
        int k0 = (kb << 5) + (q << 3);
        const u16* ap = (k0 < 1024) ? (a2_ih + k0) : (a2_hh + (k0 - 1024));
        const u16* bp = (k0 < 1024) ? (b_h1 + k0) : (b_h2 + k0);
        acc2 = __builtin_amdgcn_mfma_f32_16x16x32_bf16(
            *(const bf16x8*)ap, *(const bf16x8*)bp, acc2, 0, 0, 0);
      }
    }
    gbar(bar, grp, mygen);
  }
  // ================= EPILOGUE: finish step 511 =================
  {
    const u16* brow = ctxg + 1 * (B_ * 512) + bb * 512;  // ctx_511 in buffer 1
#pragma unroll
    for (int kb = 0; kb < 4; ++kb) {
      int k0 = ((wid * 4 + kb) << 5) + (q << 3);
      acc2 = __builtin_amdgcn_mfma_f32_16x16x32_bf16(
          a2hi[kb], *(const bf16x8*)(brow + k0), acc2, 0, 0, 0);
    }
    __syncthreads();
    *(f32x4*)&red[wid][lane][0] = acc2;
    __syncthreads();
    if (tid < 64) {
      int u = tid >> 4, bi = tid & 15;
      float gi = 0, gf = 0, gg = 0, go = 0;
#pragma unroll
      for (int w = 0; w < 4; ++w) {
        gi += red[w][bi][u];
        gf += red[w][16 + bi][u];
        gg += red[w][32 + bi][u];
        go += red[w][48 + bi][u];
      }
      int unit = u0 + u;
      gi += b2f(b2[unit]); gf += b2f(b2[1024 + unit]);
      gg += b2f(b2[2048 + unit]); go += b2f(b2[3072 + unit]);
      float cold = c2g[bi * 1024 + unit];
      float cn = sigm(gf) * cold + sigm(gi) * tanh_fast(gg);
      float hn = sigm(go) * tanh_fast(cn);
      c2g[bi * 1024 + unit] = cn;
      h2g[bi * 1024 + unit] = f2b(hn);
    }
  }
  gbar(bar, grp, mygen);
  if (wg >= 16 && wg < 49) {
    int tt = wg - 16, r0 = tt << 4;
    int rowp = r0 + m;
    int rowc = rowp > 512 ? 512 : rowp;
    const u16* ar = wproj + (long)rowc * 1536;
    const u16* br_h2 = h2g + bb * 1024;
    const u16* br_ctx = ctxg + 1 * (B_ * 512) + bb * 512 - 1024;
    f32x4 accp; accp[0] = accp[1] = accp[2] = accp[3] = 0.f;
#pragma unroll 1
    for (int kb = wid * 12; kb < wid * 12 + 12; ++kb) {
      int k0 = (kb << 5) + (q << 3);
      const u16* bp = (k0 < 1024) ? (br_h2 + k0) : (br_ctx + k0);
      accp = __builtin_amdgcn_mfma_f32_16x16x32_bf16(
          *(const bf16x8*)(ar + k0), *(const bf16x8*)bp, accp, 0, 0, 0);
    }
    __syncthreads();
    *(f32x4*)&red[wid][lane][0] = accp;
    __syncthreads();
    {
      int mm = tid >> 4, bi = tid & 15;
      int row = r0 + mm;
      if (row < FEAT_D_) {
        int l = ((mm >> 2) << 4) + bi, r = mm & 3;
        float s = red[0][l][r] + red[1][l][r] + red[2][l][r] + red[3][l][r];
        s += b2f(bproj[row]);
        outf[((long)bi * FEAT_D_ + row) * DEC_T_ + 511] = s;
      }
    }
  }
}

extern "C" void kernel_launch(void* const* d_in, const int* in_sizes, int n_in,
                              void* d_out, int out_size, void* d_ws, size_t ws_size,
                              hipStream_t stream) {
  const void* enc   = d_in[0];
  const void* feats = d_in[2];
  const void* go    = d_in[3];
  const void* w0    = d_in[4];
  const void* w1    = d_in[5];

  float* outf = (float*)d_out;                         // [16][513][512] fp32
  float* outa = outf + (size_t)B_ * FEAT_D_ * DEC_T_;  // [16][256][512] fp32

  char* ws = (char*)d_ws;
  size_t off = 0;
  auto take = [&](size_t bytes) { char* p = ws + off; off += (bytes + 255) & ~size_t(255); return p; };
  int*   flag   = (int*)take(256);
  int*   lens_d = (int*)take(256);
  u16*   pre    = (u16*)take((size_t)DEC_T_ * B_ * 256 * 2);
  u16*   mem_t  = (u16*)take((size_t)B_ * ENC_T_ * ENC_D_ * 2);
  float* pm     = (float*)take((size_t)B_ * ENC_T_ * ATT_ * 4);
  u16*   h1g    = (u16*)take((size_t)2 * B_ * 1024 * 2);
  u16*   h2g    = (u16*)take((size_t)B_ * 1024 * 2);
  u16*   ctxg   = (u16*)take((size_t)2 * B_ * 512 * 2);
  float* c1g    = (float*)take((size_t)B_ * 1024 * 4);
  float* c2g    = (float*)take((size_t)B_ * 1024 * 4);
  unsigned* bar = (unsigned*)take(2048);
  // bf16 copies of decoder weights:
  u16* wih1   = (u16*)take((size_t)4096 * 768 * 2);
  u16* whh1   = (u16*)take((size_t)4096 * 1024 * 2);
  u16* b1c    = (u16*)take((size_t)4096 * 2);
  u16* wih2   = (u16*)take((size_t)4096 * 1536 * 2);
  u16* whh2   = (u16*)take((size_t)4096 * 1024 * 2);
  u16* b2c    = (u16*)take((size_t)4096 * 2);
  u16* wqc    = (u16*)take((size_t)128 * 1024 * 2);
  u16* wconvc = (u16*)take((size_t)32 * 2 * 31 * 2);
  u16* wdensec= (u16*)take((size_t)128 * 32 * 2);
  u16* vvc    = (u16*)take((size_t)128 * 2);
  u16* wprojc = (u16*)take((size_t)513 * 1536 * 2);
  u16* bprojc = (u16*)take((size_t)513 * 2);

  k_detect<<<1, 256, 0, stream>>>((const u16*)d_in[4], flag);
  k_lens<<<1, 64, 0, stream>>>(d_in[1], lens_d);

  struct CvtJob { const void* src; u16* dst; int n; };
  const CvtJob jobs[12] = {
      {d_in[6],  wih1,   4096 * 768},
      {d_in[7],  whh1,   4096 * 1024},
      {d_in[8],  b1c,    4096},
      {d_in[9],  wih2,   4096 * 1536},
      {d_in[10], whh2,   4096 * 1024},
      {d_in[11], b2c,    4096},
      {d_in[12], wqc,    128 * 1024},
      {d_in[14], wconvc, 32 * 2 * 31},
      {d_in[15], wdensec, 128 * 32},
      {d_in[16], vvc,    128},
      {d_in[17], wprojc, 513 * 1536},
      {d_in[18], bprojc, 513},
  };
  for (int i = 0; i < 12; ++i) {
    int blocks = (jobs[i].n + 255) / 256;
    if (blocks > 512) blocks = 512;
    k_cvt<<<blocks, 256, 0, stream>>>(jobs[i].src, jobs[i].dst, jobs[i].n, flag);
  }

  k_init<<<32, 256, 0, stream>>>(h1g, h2g, ctxg, c1g, c2g, bar);
  k_prenet<<<DEC_T_, 256, 0, stream>>>(feats, go, w0, w1, pre, flag);
  k_mem<<<256, 256, 0, stream>>>(enc, d_in[13], mem_t, pm, flag);

  (void)hipFuncSetAttribute((const void*)k_main,
                            hipFuncAttributeMaxDynamicSharedMemorySize, LDS_BYTES);
  k_main<<<NWG_, 256, LDS_BYTES, stream>>>(wih1, whh1, b1c, wih2, whh2, b2c, wqc, wconvc,
                                           wdensec, vvc, wprojc, bprojc, lens_d, pre, mem_t,
                                           pm, h1g, h2g, ctxg, c1g, c2g, bar, outf, outa);
}

// Round 2
// 29237.183 us; speedup vs baseline: 2.0881x; 2.0644x over previous
//
#include <hip/hip_runtime.h>

#define B_ 16
#define ENC_D_ 512
#define ENC_T_ 256
#define FEAT_D_ 513
#define DEC_T_ 512
#define ATT_ 128
#define NWG_ 256

typedef unsigned short u16;
typedef __attribute__((ext_vector_type(8))) short bf16x8;
typedef __attribute__((ext_vector_type(4))) float f32x4;

// ---- LDS arena offsets (bytes) ----
#define S_WIH1 0            // [16][776] u16
#define S_WHH1 24832        // [16][1032] u16
#define S_WIH2 57856        // [16][1032] u16 (cols 0..1024 only; ctx cols live in VGPRs)
#define S_WHH2 90880        // [16][1032] u16
#define S_RED  123904       // float[2048]
#define S_ATT  132096       // float[2][128]
#define S_VS   133120       // float[128]
#define S_E    133632       // float[256] energies
#define S_ALN  134656       // float[256] persistent align (attn WGs)
#define S_CUM  135680       // float[256] persistent cum   (attn WGs)
#define S_SRED 136704       // float[8]
#define S_CONVF 136736      // u16 [256][32]  convf[t'][c]
#define S_WCV  153120       // u16 [32][62]   conv weights
#define LDS_BYTES 157088

__device__ __forceinline__ float b2f(u16 x) {
  unsigned u = ((unsigned)x) << 16;
  return __builtin_bit_cast(float, u);
}
__device__ __forceinline__ u16 f2b(float f) {
  unsigned u = __builtin_bit_cast(unsigned, f);
  u += 0x7FFFu + ((u >> 16) & 1u);
  return (u16)(u >> 16);
}
__device__ __forceinline__ float ldin(const void* p, long i, bool f32) {
  return f32 ? ((const float*)p)[i] : b2f(((const u16*)p)[i]);
}
__device__ __forceinline__ float sigm(float x) {
  return __builtin_amdgcn_rcpf(1.f + __expf(-x));
}
__device__ __forceinline__ float tanh_fast(float x) {
  float e = __expf(2.f * x);
  return 1.f - 2.f * __builtin_amdgcn_rcpf(e + 1.f);
}

// coherence-point load (bypasses L1+L2, sees other XCDs' sc stores).
// NOTE: result NOT ready until a following s_waitcnt vmcnt(0)!
__device__ __forceinline__ bf16x8 ldv16(const u16* p) {
  bf16x8 r;
  asm volatile("global_load_dwordx4 %0, %1, off sc0 sc1" : "=v"(r) : "v"(p));
  return r;
}
__device__ __forceinline__ void vwait() {
  asm volatile("s_waitcnt vmcnt(0)" ::: "memory");
  __builtin_amdgcn_sched_barrier(0);
}
// coherence-point 16-bit store (write-through; globally visible when vmcnt drains)
__device__ __forceinline__ void stv16(u16* p, u16 v) {
  asm volatile("global_store_short %0, %1, off sc0 sc1" :: "v"(p), "v"(v) : "memory");
}

// fence-free grid barrier: sc-stores are already at the coherence point once the
// pre-barrier s_waitcnt+s_barrier drains vmcnt, so NO wbl2/inv is needed anywhere.
// Hierarchical RELAXED monotonic counters; per-group release lines (32 pollers/line).
// bar words: sub[g]=bar[g*32] (g=0..7), root=bar[256], gen[g]=bar[320+g*32]
__device__ __forceinline__ void gbar(unsigned* bar, int grp, unsigned& mygen) {
  asm volatile("s_waitcnt vmcnt(0)" ::: "memory");
  __syncthreads();
  ++mygen;
  if (threadIdx.x == 0) {
    unsigned* sub = bar + (grp << 5);
    unsigned* root = bar + 256;
    unsigned* gen = bar + 320 + (grp << 5);
    unsigned old = __hip_atomic_fetch_add(sub, 1u, __ATOMIC_RELAXED, __HIP_MEMORY_SCOPE_AGENT);
    if (old + 1u == (mygen << 5)) {
      unsigned rold = __hip_atomic_fetch_add(root, 1u, __ATOMIC_RELAXED, __HIP_MEMORY_SCOPE_AGENT);
      if (rold + 1u == (mygen << 3)) {
#pragma unroll
        for (int g = 0; g < 8; ++g)
          __hip_atomic_store(bar + 320 + (g << 5), mygen, __ATOMIC_RELAXED, __HIP_MEMORY_SCOPE_AGENT);
      }
    }
    while (__hip_atomic_load(gen, __ATOMIC_RELAXED, __HIP_MEMORY_SCOPE_AGENT) < mygen)
      __builtin_amdgcn_s_sleep(2);
  }
  __syncthreads();
}

// float dtype detect: 0 = bf16 inputs, 1 = fp32 inputs
__global__ void k_detect(const u16* __restrict__ w, int* flag) {
  __shared__ int cnt;
  if (threadIdx.x == 0) cnt = 0;
  __syncthreads();
  int c = 0;
  for (int i = threadIdx.x; i < 512; i += 256) {
    u16 v = w[2 * i];
    int e = (v >> 7) & 0xFF;
    if (e >= 80 && e <= 140) c++;
  }
  atomicAdd(&cnt, c);
  __syncthreads();
  if (threadIdx.x == 0) *flag = (cnt >= 384) ? 0 : 1;
}

// encoding_lengths format detect
__global__ void k_lens(const void* __restrict__ raw, int* __restrict__ lens_out) {
  if (threadIdx.x != 0 || blockIdx.x != 0) return;
  const int* i32 = (const int*)raw;
  const long long* i64 = (const long long*)raw;
  const float* f32 = (const float*)raw;
  const double* f64 = (const double*)raw;
  bool ok;
  ok = true;
  for (int b = 0; b < B_; ++b) { int v = i32[b]; if (v < 1 || v > ENC_T_) ok = false; }
  if (ok) { for (int b = 0; b < B_; ++b) lens_out[b] = i32[b]; return; }
  ok = true;
  for (int b = 0; b < B_; ++b) { long long v = i64[b]; if (v < 1 || v > ENC_T_) ok = false; }
  if (ok) { for (int b = 0; b < B_; ++b) lens_out[b] = (int)i64[b]; return; }
  ok = true;
  for (int b = 0; b < B_; ++b) { float x = f32[b]; if (!(x >= 1.f && x <= 256.f && x == floorf(x))) ok = false; }
  if (ok) { for (int b = 0; b < B_; ++b) lens_out[b] = (int)f32[b]; return; }
  ok = true;
  for (int b = 0; b < B_; ++b) { double x = f64[b]; if (!(x >= 1.0 && x <= 256.0 && x == floor(x))) ok = false; }
  if (ok) { for (int b = 0; b < B_; ++b) lens_out[b] = (int)f64[b]; return; }
  for (int b = 0; b < B_; ++b) {
    int v = i32[b];
    lens_out[b] = v < 1 ? 1 : (v > ENC_T_ ? ENC_T_ : v);
  }
}

// convert one tensor to bf16 in ws
__global__ void k_cvt(const void* __restrict__ src, u16* __restrict__ dst, int n,
                      const int* __restrict__ flag) {
  bool f32 = (*flag) != 0;
  int stride = blockDim.x * gridDim.x;
  for (int i = threadIdx.x + blockIdx.x * blockDim.x; i < n; i += stride)
    dst[i] = f32 ? f2b(((const float*)src)[i]) : ((const u16*)src)[i];
}

// init: zero states + barrier words
__global__ void k_init(u16* h1g, u16* h2g, u16* ctxg, float* c1g, float* c2g, unsigned* bar) {
  int tid = threadIdx.x + blockIdx.x * blockDim.x;
  int stride = blockDim.x * gridDim.x;
  for (int i = tid; i < 2 * B_ * 1024; i += stride) h1g[i] = 0;
  for (int i = tid; i < B_ * 1024; i += stride) h2g[i] = 0;
  for (int i = tid; i < 2 * B_ * 512; i += stride) ctxg[i] = 0;
  for (int i = tid; i < B_ * 1024; i += stride) { c1g[i] = 0.f; c2g[i] = 0.f; }
  for (int i = tid; i < 1024; i += stride) bar[i] = 0u;
}

// prenet for all timesteps (teacher-forced, recurrence-free), bf16 out
__global__ __launch_bounds__(256) void k_prenet(const void* __restrict__ feats,
                                                const void* __restrict__ go,
                                                const void* __restrict__ w0,
                                                const void* __restrict__ w1,
                                                u16* __restrict__ pre,
                                                const int* __restrict__ flag) {
  const bool f32 = (*flag) != 0;
  int t = blockIdx.x, tid = threadIdx.x;
  __shared__ __align__(16) float din[FEAT_D_][16];
  __shared__ __align__(16) float o1[256][16];
  for (int idx = tid; idx < 16 * FEAT_D_; idx += 256) {
    int f = idx >> 4, b = idx & 15;
    float v = (t == 0) ? ldin(go, f, f32)
                       : ldin(feats, ((long)b * FEAT_D_ + f) * DEC_T_ + (t - 1), f32);
    din[f][b] = v;
  }
  __syncthreads();
  float acc[16];
#pragma unroll
  for (int b = 0; b < 16; ++b) acc[b] = 0.f;
  for (int f = 0; f < FEAT_D_; ++f) {
    float w = ldin(w0, (long)tid * FEAT_D_ + f, f32);
#pragma unroll
    for (int b = 0; b < 16; ++b) acc[b] += w * din[f][b];
  }
#pragma unroll
  for (int b = 0; b < 16; ++b) o1[tid][b] = fmaxf(acc[b], 0.f);
  __syncthreads();
#pragma unroll
  for (int b = 0; b < 16; ++b) acc[b] = 0.f;
  for (int r1 = 0; r1 < 256; ++r1) {
    float w = ldin(w1, (long)tid * 256 + r1, f32);
#pragma unroll
    for (int b = 0; b < 16; ++b) acc[b] += w * o1[r1][b];
  }
#pragma unroll
  for (int b = 0; b < 16; ++b)
    pre[((long)t * 16 + b) * 256 + tid] = f2b(fmaxf(acc[b], 0.f));
}

// encoder transpose (bf16) + processed-memory. pm layout: [b][a][t']
__global__ __launch_bounds__(256) void k_mem(const void* __restrict__ enc,
                                             const void* __restrict__ wmem,
                                             u16* __restrict__ mem_t,
                                             float* __restrict__ pm,
                                             const int* __restrict__ flag) {
  const bool f32 = (*flag) != 0;
  int b = blockIdx.x >> 4, tc = blockIdx.x & 15;
  int t0 = tc * 16, tid = threadIdx.x;
  __shared__ __align__(16) float et[16][ENC_D_];
  for (int idx = tid; idx < ENC_D_ * 16; idx += 256) {
    int d = idx >> 4, i = idx & 15;
    et[i][d] = ldin(enc, ((long)b * ENC_D_ + d) * ENC_T_ + t0 + i, f32);
  }
  __syncthreads();
  for (int idx = tid; idx < 16 * ENC_D_; idx += 256) {
    int i = idx >> 9, d = idx & 511;
    mem_t[((long)b * ENC_T_ + t0 + i) * ENC_D_ + d] = f2b(et[i][d]);
  }
  int a = tid & 127;
#pragma unroll 1
  for (int jj = 0; jj < 8; ++jj) {
    int i = ((tid >> 7) << 3) + jj;
    float s = 0.f;
    for (int d = 0; d < ENC_D_; ++d)
      s += ldin(wmem, (long)a * ENC_D_ + d, f32) * et[i][d];
    pm[((long)b * ATT_ + a) * ENC_T_ + t0 + i] = s;
  }
}

// ---------------- persistent decoder ----------------
__global__ __launch_bounds__(256, 1) void k_main(
    const u16* __restrict__ wih1, const u16* __restrict__ whh1, const u16* __restrict__ b1,
    const u16* __restrict__ wih2, const u16* __restrict__ whh2, const u16* __restrict__ b2,
    const u16* __restrict__ wq, const u16* __restrict__ wconv, const u16* __restrict__ wdense,
    const u16* __restrict__ vv, const u16* __restrict__ wproj, const u16* __restrict__ bproj,
    const int* __restrict__ lens,
    const u16* __restrict__ pre, const u16* __restrict__ mem_t, const float* __restrict__ pm,
    u16* h1g, u16* h2g, u16* ctxg, float* c1g, float* c2g,
    unsigned* bar, float* outf, float* outa) {
  extern __shared__ __align__(16) char smem[];
  u16* s_wih1 = (u16*)(smem + S_WIH1);
  u16* s_whh1 = (u16*)(smem + S_WHH1);
  u16* s_wih2 = (u16*)(smem + S_WIH2);
  u16* s_whh2 = (u16*)(smem + S_WHH2);
  float* red_f = (float*)(smem + S_RED);
  float (*red)[64][4] = (float(*)[64][4])red_f;
  float (*att_s)[128] = (float(*)[128])(smem + S_ATT);
  float* v_s = (float*)(smem + S_VS);
  float* e_s = (float*)(smem + S_E);
  float* align_s = (float*)(smem + S_ALN);
  float* cum_s = (float*)(smem + S_CUM);
  float* sred = (float*)(smem + S_SRED);
  u16* convf = (u16*)(smem + S_CONVF);
  u16* s_wcv = (u16*)(smem + S_WCV);

  const int wg = blockIdx.x, tid = threadIdx.x;
  const int wid = tid >> 6, lane = tid & 63;
  const int m = lane & 15, q = lane >> 4;
  const int u0 = wg << 2;
  const int bb = m;
  const int grp = wg & 7;

  // ---- stage weight rows into LDS (wih2: only cols 0..1024) ----
  for (int r = 0; r < 4; ++r) {
    int m2 = wid * 4 + r;
    int growr = ((m2 >> 2) << 10) + u0 + (m2 & 3);
    {
      const u16* s = wih1 + (long)growr * 768; u16* d = s_wih1 + m2 * 776;
      for (int c = lane; c < 96; c += 64) *(bf16x8*)(d + c * 8) = *(const bf16x8*)(s + c * 8);
    }
    {
      const u16* s = whh1 + (long)growr * 1024; u16* d = s_whh1 + m2 * 1032;
      for (int c = lane; c < 128; c += 64) *(bf16x8*)(d + c * 8) = *(const bf16x8*)(s + c * 8);
    }
    {
      const u16* s = wih2 + (long)growr * 1536; u16* d = s_wih2 + m2 * 1032;
      for (int c = lane; c < 128; c += 64) *(bf16x8*)(d + c * 8) = *(const bf16x8*)(s + c * 8);
    }
    {
      const u16* s = whh2 + (long)growr * 1024; u16* d = s_whh2 + m2 * 1032;
      for (int c = lane; c < 128; c += 64) *(bf16x8*)(d + c * 8) = *(const bf16x8*)(s + c * 8);
    }
  }
  // Wih2 ctx-columns (1024..1536) per-lane A-fragments in VGPRs
  bf16x8 a2hi[4];
  {
    int growr = ((m >> 2) << 10) + u0 + (m & 3);
#pragma unroll
    for (int kb = 0; kb < 4; ++kb) {
      int k0 = ((wid * 4 + kb) << 5) + (q << 3);
      a2hi[kb] = *(const bf16x8*)(wih2 + (long)growr * 1536 + 1024 + k0);
    }
  }
  // conv weights + v to LDS; attn WGs init persistent align/cum
  for (int i = tid; i < 32 * 62; i += 256) s_wcv[i] = wconv[i];
  if (tid < 128) v_s[tid] = b2f(vv[tid]);
  if (wg < B_) {
    for (int i = tid; i < ENC_T_; i += 256) {
      float v = (i == 0) ? 1.f : 0.f;
      align_s[i] = v; cum_s[i] = v;
    }
  }
  const int len_b = (wg < B_) ? lens[wg] : 0;
  __syncthreads();

  unsigned mygen = 0;
  f32x4 zero4; zero4[0] = zero4[1] = zero4[2] = zero4[3] = 0.f;
  f32x4 acc2 = zero4;

  const u16* a1_ih = s_wih1 + m * 776;
  const u16* a1_hh = s_whh1 + m * 1032;
  const u16* a2_ih = s_wih2 + m * 1032;
  const u16* a2_hh = s_whh2 + m * 1032;

#pragma unroll 1
  for (int t = 0; t < DEC_T_; ++t) {
    const int cb = t & 1, pb = cb ^ 1;
    // ================= PHASE A =================
    // (1) finish gates2(t-1): += Wih2[:,1024:1536] @ ctx_{t-1}; update h2,c2
    if (t > 0) {
      u16* brow = ctxg + pb * (B_ * 512) + bb * 512;
      bf16x8 bf[4];
#pragma unroll
      for (int kb = 0; kb < 4; ++kb) {
        int k0 = ((wid * 4 + kb) << 5) + (q << 3);
        bf[kb] = ldv16(brow + k0);
      }
      vwait();
#pragma unroll
      for (int kb = 0; kb < 4; ++kb)
        acc2 = __builtin_amdgcn_mfma_f32_16x16x32_bf16(a2hi[kb], bf[kb], acc2, 0, 0, 0);
      __syncthreads();
      *(f32x4*)&red[wid][lane][0] = acc2;
      __syncthreads();
      if (tid < 64) {
        int u = tid >> 4, bi = tid & 15;
        float gi = 0, gf = 0, gg = 0, go = 0;
#pragma unroll
        for (int w = 0; w < 4; ++w) {
          gi += red[w][bi][u];
          gf += red[w][16 + bi][u];
          gg += red[w][32 + bi][u];
          go += red[w][48 + bi][u];
        }
        int unit = u0 + u;
        gi += b2f(b2[unit]); gf += b2f(b2[1024 + unit]);
        gg += b2f(b2[2048 + unit]); go += b2f(b2[3072 + unit]);
        float cold = c2g[bi * 1024 + unit];
        float cn = sigm(gf) * cold + sigm(gi) * tanh_fast(gg);
        float hn = sigm(go) * tanh_fast(cn);
        c2g[bi * 1024 + unit] = cn;
        stv16(h2g + bi * 1024 + unit, f2b(hn));
      }
      acc2 = zero4;
    }
    // (2) location conv for own batch -> convf[t'][c] (attn WGs only; LDS-local).
    // c = tid&31 -> LDS reads are 32-lane broadcasts (bank-conflict-free).
    if (wg < B_) {
      int c = tid & 31;
      int g8 = tid >> 5;
      float w0[31], w1[31];
      const u16* wc = s_wcv + c * 62;
#pragma unroll
      for (int k = 0; k < 31; ++k) { w0[k] = b2f(wc[k]); w1[k] = b2f(wc[31 + k]); }
#pragma unroll 1
      for (int sub = 0; sub < 4; ++sub) {
        int tb = (g8 << 5) + (sub << 3);
        float xa[38], xc[38];
#pragma unroll
        for (int j = 0; j < 38; ++j) {
          int idx = tb + j - 15;
          bool ok = (idx >= 0) && (idx < ENC_T_);
          xa[j] = ok ? align_s[idx] : 0.f;
          xc[j] = ok ? cum_s[idx] : 0.f;
        }
        float acc[8];
#pragma unroll
        for (int j = 0; j < 8; ++j) acc[j] = 0.f;
#pragma unroll
        for (int k = 0; k < 31; ++k) {
#pragma unroll
          for (int j = 0; j < 8; ++j)
            acc[j] = fmaf(w0[k], xa[j + k], fmaf(w1[k], xc[j + k], acc[j]));
        }
#pragma unroll
        for (int j = 0; j < 8; ++j) convf[(tb + j) * 32 + c] = f2b(acc[j]);
      }
    }
    // (3) gates1: Wih1 @ [pre_t | ctx_{t-1}] + Whh1 @ h1_{t-1}; update h1,c1
    {
      f32x4 acc1 = zero4;
      const u16* b_pre = pre + ((long)t * B_ + bb) * 256;
      const u16* b_ctx = ctxg + pb * (B_ * 512) + bb * 512 - 256;
      const u16* b_h1 = h1g + pb * (B_ * 1024) + bb * 1024 - 768;
      bf16x8 bf[14];
#pragma unroll
      for (int i = 0; i < 14; ++i) {
        int k0 = ((wid * 14 + i) << 5) + (q << 3);
        if (k0 < 256) bf[i] = *(const bf16x8*)(b_pre + k0);
        else bf[i] = ldv16((k0 < 768 ? b_ctx : b_h1) + k0);
      }
      vwait();
#pragma unroll
      for (int i = 0; i < 14; ++i) {
        int k0 = ((wid * 14 + i) << 5) + (q << 3);
        const u16* ap = (k0 < 768) ? (a1_ih + k0) : (a1_hh + (k0 - 768));
        acc1 = __builtin_amdgcn_mfma_f32_16x16x32_bf16(
            *(const bf16x8*)ap, bf[i], acc1, 0, 0, 0);
      }
      __syncthreads();
      *(f32x4*)&red[wid][lane][0] = acc1;
      __syncthreads();
      if (tid < 64) {
        int u = tid >> 4, bi = tid & 15;
        float gi = 0, gf = 0, gg = 0, go = 0;
#pragma unroll
        for (int w = 0; w < 4; ++w) {
          gi += red[w][bi][u];
          gf += red[w][16 + bi][u];
          gg += red[w][32 + bi][u];
          go += red[w][48 + bi][u];
        }
        int unit = u0 + u;
        gi += b2f(b1[unit]); gf += b2f(b1[1024 + unit]);
        gg += b2f(b1[2048 + unit]); go += b2f(b1[3072 + unit]);
        float cold = c1g[bi * 1024 + unit];
        float cn = sigm(gf) * cold + sigm(gi) * tanh_fast(gg);
        float hn = sigm(go) * tanh_fast(cn);
        c1g[bi * 1024 + unit] = cn;
        stv16(h1g + cb * (B_ * 1024) + bi * 1024 + unit, f2b(hn));
      }
    }
    gbar(bar, grp, mygen);
    // ================= PHASE B =================
    if (wg < B_) {
      const int ab = wg;
      // stage fresh h1 row (1024 bf16) into LDS via coherence-point loads
      u16* h1row = (u16*)red_f;
      if (tid < 128) {
        bf16x8 v = ldv16(h1g + (long)cb * (B_ * 1024) + ab * 1024 + tid * 8);
        asm volatile("s_waitcnt vmcnt(0)" ::: "memory");
        *(bf16x8*)(h1row + tid * 8) = v;
      }
      __syncthreads();
      // query projection (wq stays warm in L1/L2 — no invalidates anymore)
      {
        int a = tid & 127, h = tid >> 7;
        const u16* wr = wq + (long)a * 1024 + h * 512;
        const u16* hr = h1row + h * 512;
        float p = 0.f;
        for (int k = 0; k < 512; k += 8) {
          bf16x8 w8 = *(const bf16x8*)(wr + k);
          bf16x8 h8 = *(const bf16x8*)(hr + k);
#pragma unroll
          for (int j = 0; j < 8; ++j) p += b2f((u16)w8[j]) * b2f((u16)h8[j]);
        }
        att_s[h][a] = p;
      }
      __syncthreads();
      if (tid < 128) att_s[0][tid] += att_s[1][tid];
      __syncthreads();
      // energies: lf via MFMA (wdense[a][c] x convf[t'][c]) + pm + pq -> tanh -> dot v
      {
        const int col = lane & 15, hi2 = lane >> 4;
#pragma unroll 1
        for (int ti = 0; ti < 4; ++ti) {
          int t0 = (wid * 4 + ti) << 4;
          if (t0 >= len_b) break;
          bf16x8 bfrag = *(const bf16x8*)(convf + (t0 + col) * 32 + (hi2 << 3));
          float eacc = 0.f;
#pragma unroll
          for (int at = 0; at < 8; ++at) {
            bf16x8 afrag = *(const bf16x8*)(wdense + ((at * 16 + col) << 5) + (hi2 << 3));
            f32x4 lf = __builtin_amdgcn_mfma_f32_16x16x32_bf16(afrag, bfrag, zero4, 0, 0, 0);
#pragma unroll
            for (int r = 0; r < 4; ++r) {
              int a = at * 16 + (hi2 << 2) + r;
              float s = lf[r] + pm[((long)ab * ATT_ + a) * ENC_T_ + t0 + col] + att_s[0][a];
              eacc = fmaf(v_s[a], tanh_fast(s), eacc);
            }
          }
          eacc += __shfl_xor(eacc, 16);
          eacc += __shfl_xor(eacc, 32);
          if (hi2 == 0) e_s[t0 + col] = eacc;
        }
      }
      __syncthreads();
      // softmax over 256 positions
      float e = (tid < len_b) ? e_s[tid] : -1e9f;
      float mx = e;
#pragma unroll
      for (int off = 32; off; off >>= 1) mx = fmaxf(mx, __shfl_xor(mx, off));
      if (lane == 0) sred[wid] = mx;
      __syncthreads();
      mx = fmaxf(fmaxf(sred[0], sred[1]), fmaxf(sred[2], sred[3]));
      float ex = __expf(e - mx);
      float sm = ex;
#pragma unroll
      for (int off = 32; off; off >>= 1) sm += __shfl_xor(sm, off);
      if (lane == 0) sred[4 + wid] = sm;
      __syncthreads();
      sm = sred[4] + sred[5] + sred[6] + sred[7];
      float al = ex / sm;
      align_s[tid] = al;
      cum_s[tid] += al;
      outa[((long)ab * ENC_T_ + tid) * DEC_T_ + t] = al;
      __syncthreads();
      {
        // ctx = align @ mem_t (len-clamped; mem_t stays cache-warm)
        int g = tid & 63, qd = tid >> 6;
        const u16* mt = mem_t + (long)ab * (ENC_T_ * ENC_D_) + g * 8;
        float a8[8];
#pragma unroll
        for (int j = 0; j < 8; ++j) a8[j] = 0.f;
        int tp0 = qd * 64;
        int tpe = tp0 + 64;
        if (tpe > len_b) tpe = (len_b > tp0) ? len_b : tp0;
#pragma unroll 2
        for (int tp = tp0; tp < tpe; ++tp) {
          float av = align_s[tp];
          bf16x8 m8 = *(const bf16x8*)(mt + (long)tp * ENC_D_);
#pragma unroll
          for (int j = 0; j < 8; ++j) a8[j] = fmaf(av, b2f((u16)m8[j]), a8[j]);
        }
#pragma unroll
        for (int j = 0; j < 8; ++j) red_f[qd * 512 + g * 8 + j] = a8[j];
        __syncthreads();
        for (int d = tid; d < 512; d += 256) {
          float s = red_f[d] + red_f[512 + d] + red_f[1024 + d] + red_f[1536 + d];
          stv16(ctxg + cb * (B_ * 512) + ab * 512 + d, f2b(s));
        }
      }
    }
    if (wg >= 16 && wg < 49 && t > 0) {
      // proj(t-1)
      int tt = wg - 16, r0 = tt << 4;
      int rowp = r0 + m;
      int rowc = rowp > 512 ? 512 : rowp;
      const u16* ar = wproj + (long)rowc * 1536;
      const u16* br_h2 = h2g + bb * 1024;
      const u16* br_ctx = ctxg + pb * (B_ * 512) + bb * 512 - 1024;
      f32x4 accp = zero4;
      bf16x8 bf[12];
#pragma unroll
      for (int i = 0; i < 12; ++i) {
        int k0 = ((wid * 12 + i) << 5) + (q << 3);
        bf[i] = ldv16((k0 < 1024 ? br_h2 : br_ctx) + k0);
      }
      vwait();
#pragma unroll
      for (int i = 0; i < 12; ++i) {
        int k0 = ((wid * 12 + i) << 5) + (q << 3);
        accp = __builtin_amdgcn_mfma_f32_16x16x32_bf16(
            *(const bf16x8*)(ar + k0), bf[i], accp, 0, 0, 0);
      }
      __syncthreads();
      *(f32x4*)&red[wid][lane][0] = accp;
      __syncthreads();
      {
        int mm = tid >> 4, bi = tid & 15;
        int row = r0 + mm;
        if (row < FEAT_D_) {
          int l = ((mm >> 2) << 4) + bi, r = mm & 3;
          float s = red[0][l][r] + red[1][l][r] + red[2][l][r] + red[3][l][r];
          s += b2f(bproj[row]);
          outf[((long)bi * FEAT_D_ + row) * DEC_T_ + (t - 1)] = s;
        }
      }
    }
    // gates2 partial for step t: Wih2[:,0:1024] @ h1_t + Whh2 @ h2_{t-1}
    {
      const u16* b_h1 = h1g + cb * (B_ * 1024) + bb * 1024;
      const u16* b_h2 = h2g + bb * 1024 - 1024;
      bf16x8 bg[16];
#pragma unroll
      for (int i = 0; i < 16; ++i) {
        int k0 = ((wid * 16 + i) << 5) + (q << 3);
        bg[i] = ldv16((k0 < 1024 ? b_h1 : b_h2) + k0);
      }
      vwait();
#pragma unroll
      for (int i = 0; i < 16; ++i) {
        int k0 = ((wid * 16 + i) << 5) + (q << 3);
        const u16* ap = (k0 < 1024) ? (a2_ih + k0) : (a2_hh + (k0 - 1024));
        acc2 = __builtin_amdgcn_mfma_f32_16x16x32_bf16(
            *(const bf16x8*)ap, bg[i], acc2, 0, 0, 0);
      }
    }
    gbar(bar, grp, mygen);
  }
  // ================= EPILOGUE: finish step 511 =================
  {
    u16* brow = ctxg + 1 * (B_ * 512) + bb * 512;  // ctx_511 in buffer 1
    bf16x8 bf[4];
#pragma unroll
    for (int kb = 0; kb < 4; ++kb) {
      int k0 = ((wid * 4 + kb) << 5) + (q << 3);
      bf[kb] = ldv16(brow + k0);
    }
    vwait();
#pragma unroll
    for (int kb = 0; kb < 4; ++kb)
      acc2 = __builtin_amdgcn_mfma_f32_16x16x32_bf16(a2hi[kb], bf[kb], acc2, 0, 0, 0);
    __syncthreads();
    *(f32x4*)&red[wid][lane][0] = acc2;
    __syncthreads();
    if (tid < 64) {
      int u = tid >> 4, bi = tid & 15;
      float gi = 0, gf = 0, gg = 0, go = 0;
#pragma unroll
      for (int w = 0; w < 4; ++w) {
        gi += red[w][bi][u];
        gf += red[w][16 + bi][u];
        gg += red[w][32 + bi][u];
        go += red[w][48 + bi][u];
      }
      int unit = u0 + u;
      gi += b2f(b2[unit]); gf += b2f(b2[1024 + unit]);
      gg += b2f(b2[2048 + unit]); go += b2f(b2[3072 + unit]);
      float cold = c2g[bi * 1024 + unit];
      float cn = sigm(gf) * cold + sigm(gi) * tanh_fast(gg);
      float hn = sigm(go) * tanh_fast(cn);
      c2g[bi * 1024 + unit] = cn;
      stv16(h2g + bi * 1024 + unit, f2b(hn));
    }
  }
  gbar(bar, grp, mygen);
  if (wg >= 16 && wg < 49) {
    int tt = wg - 16, r0 = tt << 4;
    int rowp = r0 + m;
    int rowc = rowp > 512 ? 512 : rowp;
    const u16* ar = wproj + (long)rowc * 1536;
    const u16* br_h2 = h2g + bb * 1024;
    const u16* br_ctx = ctxg + 1 * (B_ * 512) + bb * 512 - 1024;
    f32x4 accp; accp[0] = accp[1] = accp[2] = accp[3] = 0.f;
    bf16x8 bf[12];
#pragma unroll
    for (int i = 0; i < 12; ++i) {
      int k0 = ((wid * 12 + i) << 5) + (q << 3);
      bf[i] = ldv16((k0 < 1024 ? br_h2 : br_ctx) + k0);
    }
    vwait();
#pragma unroll
    for (int i = 0; i < 12; ++i) {
      int k0 = ((wid * 12 + i) << 5) + (q << 3);
      accp = __builtin_amdgcn_mfma_f32_16x16x32_bf16(
          *(const bf16x8*)(ar + k0), bf[i], accp, 0, 0, 0);
    }
    __syncthreads();
    *(f32x4*)&red[wid][lane][0] = accp;
    __syncthreads();
    {
      int mm = tid >> 4, bi = tid & 15;
      int row = r0 + mm;
      if (row < FEAT_D_) {
        int l = ((mm >> 2) << 4) + bi, r = mm & 3;
        float s = red[0][l][r] + red[1][l][r] + red[2][l][r] + red[3][l][r];
        s += b2f(bproj[row]);
        outf[((long)bi * FEAT_D_ + row) * DEC_T_ + 511] = s;
      }
    }
  }
}

extern "C" void kernel_launch(void* const* d_in, const int* in_sizes, int n_in,
                              void* d_out, int out_size, void* d_ws, size_t ws_size,
                              hipStream_t stream) {
  const void* enc   = d_in[0];
  const void* feats = d_in[2];
  const void* go    = d_in[3];
  const void* w0    = d_in[4];
  const void* w1    = d_in[5];

  float* outf = (float*)d_out;                         // [16][513][512] fp32
  float* outa = outf + (size_t)B_ * FEAT_D_ * DEC_T_;  // [16][256][512] fp32

  char* ws = (char*)d_ws;
  size_t off = 0;
  auto take = [&](size_t bytes) { char* p = ws + off; off += (bytes + 255) & ~size_t(255); return p; };
  int*   flag   = (int*)take(256);
  int*   lens_d = (int*)take(256);
  u16*   pre    = (u16*)take((size_t)DEC_T_ * B_ * 256 * 2);
  u16*   mem_t  = (u16*)take((size_t)B_ * ENC_T_ * ENC_D_ * 2);
  float* pm     = (float*)take((size_t)B_ * ENC_T_ * ATT_ * 4);
  u16*   h1g    = (u16*)take((size_t)2 * B_ * 1024 * 2);
  u16*   h2g    = (u16*)take((size_t)B_ * 1024 * 2);
  u16*   ctxg   = (u16*)take((size_t)2 * B_ * 512 * 2);
  float* c1g    = (float*)take((size_t)B_ * 1024 * 4);
  float* c2g    = (float*)take((size_t)B_ * 1024 * 4);
  unsigned* bar = (unsigned*)take(4096);
  // bf16 copies of decoder weights:
  u16* wih1   = (u16*)take((size_t)4096 * 768 * 2);
  u16* whh1   = (u16*)take((size_t)4096 * 1024 * 2);
  u16* b1c    = (u16*)take((size_t)4096 * 2);
  u16* wih2   = (u16*)take((size_t)4096 * 1536 * 2);
  u16* whh2   = (u16*)take((size_t)4096 * 1024 * 2);
  u16* b2c    = (u16*)take((size_t)4096 * 2);
  u16* wqc    = (u16*)take((size_t)128 * 1024 * 2);
  u16* wconvc = (u16*)take((size_t)32 * 2 * 31 * 2);
  u16* wdensec= (u16*)take((size_t)128 * 32 * 2);
  u16* vvc    = (u16*)take((size_t)128 * 2);
  u16* wprojc = (u16*)take((size_t)513 * 1536 * 2);
  u16* bprojc = (u16*)take((size_t)513 * 2);

  k_detect<<<1, 256, 0, stream>>>((const u16*)d_in[4], flag);
  k_lens<<<1, 64, 0, stream>>>(d_in[1], lens_d);

  struct CvtJob { const void* src; u16* dst; int n; };
  const CvtJob jobs[12] = {
      {d_in[6],  wih1,   4096 * 768},
      {d_in[7],  whh1,   4096 * 1024},
      {d_in[8],  b1c,    4096},
      {d_in[9],  wih2,   4096 * 1536},
      {d_in[10], whh2,   4096 * 1024},
      {d_in[11], b2c,    4096},
      {d_in[12], wqc,    128 * 1024},
      {d_in[14], wconvc, 32 * 2 * 31},
      {d_in[15], wdensec, 128 * 32},
      {d_in[16], vvc,    128},
      {d_in[17], wprojc, 513 * 1536},
      {d_in[18], bprojc, 513},
  };
  for (int i = 0; i < 12; ++i) {
    int blocks = (jobs[i].n + 255) / 256;
    if (blocks > 512) blocks = 512;
    k_cvt<<<blocks, 256, 0, stream>>>(jobs[i].src, jobs[i].dst, jobs[i].n, flag);
  }

  k_init<<<32, 256, 0, stream>>>(h1g, h2g, ctxg, c1g, c2g, bar);
  k_prenet<<<DEC_T_, 256, 0, stream>>>(feats, go, w0, w1, pre, flag);
  k_mem<<<256, 256, 0, stream>>>(enc, d_in[13], mem_t, pm, flag);

  (void)hipFuncSetAttribute((const void*)k_main,
                            hipFuncAttributeMaxDynamicSharedMemorySize, LDS_BYTES);
  k_main<<<NWG_, 256, LDS_BYTES, stream>>>(wih1, whh1, b1c, wih2, whh2, b2c, wqc, wconvc,
                                           wdensec, vvc, wprojc, bprojc, lens_d, pre, mem_t,
                                           pm, h1g, h2g, ctxg, c1g, c2g, bar, outf, outa);
}